// Round 1
// baseline (613.808 us; speedup 1.0000x reference)
//
#include <hip/hip_runtime.h>

#define NB 32     // batch
#define NS 256    // 2d seq
#define NT 512    // text seq
#define KD3 256   // d3d
#define KD2 768   // d2d
#define NP 3072   // proj dim (= DTEXT)
#define KFZ 9216  // 3*NP fused K

// ---------------- K1: f3p[b,p] = feat_3d[b,:] . W3d[p,:] + b3d[p] -> concat[b][0:3072]
__global__ __launch_bounds__(256) void k1_f3p(const float* __restrict__ f3d,
                                              const float* __restrict__ W3d,
                                              const float* __restrict__ b3d,
                                              float* __restrict__ concatb) {
  int b = blockIdx.x & 31, pc = blockIdx.x >> 5;  // 32 b x 12 pc
  __shared__ float4 xs[KD3 / 4];
  int tid = threadIdx.x;
  if (tid < KD3 / 4) xs[tid] = ((const float4*)(f3d + b * KD3))[tid];
  __syncthreads();
  int p = pc * 256 + tid;
  const float4* wrow = (const float4*)(W3d + (size_t)p * KD3);
  float acc = b3d[p];
#pragma unroll 8
  for (int i = 0; i < KD3 / 4; ++i) {
    float4 w = wrow[i], x = xs[i];
    acc = fmaf(w.x, x.x, acc); acc = fmaf(w.y, x.y, acc);
    acc = fmaf(w.z, x.z, acc); acc = fmaf(w.w, x.w, acc);
  }
  concatb[(size_t)b * KFZ + p] = acc;
}

// ---------------- K2: g_part[kc][b][d] = sum_{p in chunk} W2d[p,d]*f3p[b,p]
// grid = 3 dc * 32 kc = 96 blocks; chunk = 96 p
__global__ __launch_bounds__(256) void k2_gpart(const float* __restrict__ W2d,
                                                const float* __restrict__ concatb,
                                                float* __restrict__ g_part) {
  int dc = blockIdx.x % 3, kc = blockIdx.x / 3;
  __shared__ float xs[NB * 96];
  int tid = threadIdx.x;
  int p0 = kc * 96;
  for (int i = tid; i < NB * 96; i += 256) {
    int bb = i / 96, pp = i - bb * 96;
    xs[i] = concatb[(size_t)bb * KFZ + p0 + pp];
  }
  __syncthreads();
  int d = dc * 256 + tid;
  float acc[NB];
#pragma unroll
  for (int b = 0; b < NB; ++b) acc[b] = 0.f;
  for (int pp = 0; pp < 96; pp += 4) {
    float w0 = W2d[(size_t)(p0 + pp + 0) * KD2 + d];
    float w1 = W2d[(size_t)(p0 + pp + 1) * KD2 + d];
    float w2 = W2d[(size_t)(p0 + pp + 2) * KD2 + d];
    float w3 = W2d[(size_t)(p0 + pp + 3) * KD2 + d];
#pragma unroll
    for (int b = 0; b < NB; ++b) {
      float4 x4 = *(const float4*)&xs[b * 96 + pp];
      acc[b] = fmaf(w0, x4.x, acc[b]); acc[b] = fmaf(w1, x4.y, acc[b]);
      acc[b] = fmaf(w2, x4.z, acc[b]); acc[b] = fmaf(w3, x4.w, acc[b]);
    }
  }
#pragma unroll
  for (int b = 0; b < NB; ++b) g_part[(size_t)(kc * NB + b) * KD2 + d] = acc[b];
}

// ---------------- K3a: scores_s[b,s] = feat_2d[b,s,:] . g[b,:]
// grid = 32 b * 4 sc = 128; block 256 (4 waves, 16 s each)
__global__ __launch_bounds__(256) void k3a_scores(const float* __restrict__ f2d,
                                                  const float* __restrict__ g_part,
                                                  float* __restrict__ w_s) {
  int b = blockIdx.x & 31, sc = blockIdx.x >> 5;
  __shared__ float g[KD2];
  int tid = threadIdx.x;
  for (int i = tid; i < KD2; i += 256) {
    float a = 0.f;
    for (int c = 0; c < 32; ++c) a += g_part[(size_t)(c * NB + b) * KD2 + i];
    g[i] = a;
  }
  __syncthreads();
  int wave = tid >> 6, lane = tid & 63;
  for (int i = 0; i < 16; ++i) {
    int s = sc * 64 + wave * 16 + i;
    const float4* row = (const float4*)(f2d + ((size_t)b * NS + s) * KD2);
    float acc = 0.f;
#pragma unroll
    for (int j = 0; j < 3; ++j) {
      float4 v = row[lane + 64 * j];
      float4 gg = *(const float4*)&g[4 * (lane + 64 * j)];
      acc = fmaf(v.x, gg.x, acc); acc = fmaf(v.y, gg.y, acc);
      acc = fmaf(v.z, gg.z, acc); acc = fmaf(v.w, gg.w, acc);
    }
#pragma unroll
    for (int o = 32; o; o >>= 1) acc += __shfl_xor(acc, o, 64);
    if (lane == 0) w_s[b * NS + s] = acc;
  }
}

// ---------------- softmax in place over N values, one block per b, N threads
template <int N>
__global__ __launch_bounds__(N) void k_softmax(float* __restrict__ w) {
  int b = blockIdx.x, tid = threadIdx.x;
  __shared__ float sm[N / 64];
  __shared__ float stat[2];
  float v = w[(size_t)b * N + tid];
  int wave = tid >> 6, lane = tid & 63;
  float m = v;
#pragma unroll
  for (int o = 32; o; o >>= 1) m = fmaxf(m, __shfl_xor(m, o, 64));
  if (lane == 0) sm[wave] = m;
  __syncthreads();
  if (tid == 0) {
    float mm = sm[0];
    for (int i = 1; i < N / 64; ++i) mm = fmaxf(mm, sm[i]);
    stat[0] = mm;
  }
  __syncthreads();
  float e = __expf(v - stat[0]);
  float s = e;
#pragma unroll
  for (int o = 32; o; o >>= 1) s += __shfl_xor(s, o, 64);
  __syncthreads();  // protect sm reuse
  if (lane == 0) sm[wave] = s;
  __syncthreads();
  if (tid == 0) {
    float ss = 0.f;
    for (int i = 0; i < N / 64; ++i) ss += sm[i];
    stat[1] = ss;
  }
  __syncthreads();
  w[(size_t)b * N + tid] = e / stat[1];
}

// ---------------- K3c: pooled_feat2d[b,d] = sum_s w_s[b,s]*feat_2d[b,s,d]
__global__ __launch_bounds__(256) void k3c_pool2f(const float* __restrict__ f2d,
                                                  const float* __restrict__ w_s,
                                                  float* __restrict__ p2f) {
  int b = blockIdx.x / 3, dc = blockIdx.x % 3;
  __shared__ float w[NS];
  int tid = threadIdx.x;
  w[tid] = w_s[b * NS + tid];
  __syncthreads();
  int d = dc * 256 + tid;
  float acc = 0.f;
  for (int s = 0; s < NS; ++s)
    acc = fmaf(w[s], f2d[((size_t)b * NS + s) * KD2 + d], acc);
  p2f[b * KD2 + d] = acc;
}

// ---------------- K4a: scores_t[b,t] = feat_text[b,t,:] . f3p[b,:]
// grid 32 b * 8 tc = 256 blocks
__global__ __launch_bounds__(256) void k4a_scorest(const float* __restrict__ ftx,
                                                   const float* __restrict__ concatb,
                                                   float* __restrict__ w_t) {
  int b = blockIdx.x & 31, tc = blockIdx.x >> 5;
  __shared__ float4 f3[NP / 4];
  int tid = threadIdx.x;
  for (int i = tid; i < NP / 4; i += 256)
    f3[i] = ((const float4*)(concatb + (size_t)b * KFZ))[i];
  __syncthreads();
  int wave = tid >> 6, lane = tid & 63;
  for (int i = 0; i < 16; ++i) {
    int t = tc * 64 + wave * 16 + i;
    const float4* row = (const float4*)(ftx + ((size_t)b * NT + t) * NP);
    float acc = 0.f;
#pragma unroll
    for (int j = 0; j < 12; ++j) {
      float4 v = row[lane + 64 * j];
      float4 gg = f3[lane + 64 * j];
      acc = fmaf(v.x, gg.x, acc); acc = fmaf(v.y, gg.y, acc);
      acc = fmaf(v.z, gg.z, acc); acc = fmaf(v.w, gg.w, acc);
    }
#pragma unroll
    for (int o = 32; o; o >>= 1) acc += __shfl_xor(acc, o, 64);
    if (lane == 0) w_t[b * NT + t] = acc;
  }
}

// ---------------- K4c: pt_part[tc][b][p] = sum_{t in chunk} w_t[b,t]*feat_text[b,t,p]
// grid 32 b * 3 pc * 4 tc = 384 blocks; float4 over p
__global__ __launch_bounds__(256) void k4c_poolt(const float* __restrict__ ftx,
                                                 const float* __restrict__ w_t,
                                                 float* __restrict__ ptp) {
  int b = blockIdx.x & 31;
  int r = blockIdx.x >> 5;
  int pc = r % 3, tc = r / 3;
  __shared__ float w[128];
  int tid = threadIdx.x;
  if (tid < 128) w[tid] = w_t[b * NT + tc * 128 + tid];
  __syncthreads();
  int p4 = pc * 1024 + 4 * tid;
  float4 acc = {0.f, 0.f, 0.f, 0.f};
  const float* base = ftx + ((size_t)b * NT + tc * 128) * NP + p4;
  for (int tt = 0; tt < 128; ++tt) {
    float4 v = *(const float4*)(base + (size_t)tt * NP);
    float ww = w[tt];
    acc.x = fmaf(ww, v.x, acc.x); acc.y = fmaf(ww, v.y, acc.y);
    acc.z = fmaf(ww, v.z, acc.z); acc.w = fmaf(ww, v.w, acc.w);
  }
  *(float4*)(ptp + (size_t)(tc * NB + b) * NP + p4) = acc;
}

// ---------------- K4d: pooled_text reduce -> concat[b][6144 + p]
__global__ __launch_bounds__(256) void k4d_red(const float* __restrict__ ptp,
                                               float* __restrict__ concatb) {
  int b = blockIdx.x & 31, pc = blockIdx.x >> 5;
  int p = pc * 256 + threadIdx.x;
  float a = 0.f;
#pragma unroll
  for (int c = 0; c < 4; ++c) a += ptp[(size_t)(c * NB + b) * NP + p];
  concatb[(size_t)b * KFZ + 2 * NP + p] = a;
}

// ---------------- K5: pooled_2d[b,p] = p2f[b,:] . W2d[p,:] + b2d[p] -> concat[b][3072+p]
// grid 384: bh (16-b half) * 192 pb (16 p each); wave-per-p
__global__ __launch_bounds__(256) void k5_pool2d(const float* __restrict__ W2d,
                                                 const float* __restrict__ b2d,
                                                 const float* __restrict__ p2f,
                                                 float* __restrict__ concatb) {
  int bh = blockIdx.x & 1, pb = blockIdx.x >> 1;
  __shared__ float xs[16 * KD2];
  int tid = threadIdx.x;
  for (int i = tid; i < 16 * KD2; i += 256) xs[i] = p2f[(size_t)(bh * 16) * KD2 + i];
  __syncthreads();
  int wave = tid >> 6, lane = tid & 63;
  for (int pi = 0; pi < 4; ++pi) {
    int p = pb * 16 + wave * 4 + pi;
    const float4* row = (const float4*)(W2d + (size_t)p * KD2);
    float4 wv0 = row[lane], wv1 = row[lane + 64], wv2 = row[lane + 128];
    for (int bb = 0; bb < 16; ++bb) {
      const float* xb = &xs[bb * KD2];
      float4 x0 = *(const float4*)&xb[4 * lane];
      float4 x1 = *(const float4*)&xb[4 * (lane + 64)];
      float4 x2 = *(const float4*)&xb[4 * (lane + 128)];
      float acc = 0.f;
      acc = fmaf(wv0.x, x0.x, acc); acc = fmaf(wv0.y, x0.y, acc);
      acc = fmaf(wv0.z, x0.z, acc); acc = fmaf(wv0.w, x0.w, acc);
      acc = fmaf(wv1.x, x1.x, acc); acc = fmaf(wv1.y, x1.y, acc);
      acc = fmaf(wv1.z, x1.z, acc); acc = fmaf(wv1.w, x1.w, acc);
      acc = fmaf(wv2.x, x2.x, acc); acc = fmaf(wv2.y, x2.y, acc);
      acc = fmaf(wv2.z, x2.z, acc); acc = fmaf(wv2.w, x2.w, acc);
#pragma unroll
      for (int o = 32; o; o >>= 1) acc += __shfl_xor(acc, o, 64);
      if (lane == 0)
        concatb[(size_t)(bh * 16 + bb) * KFZ + NP + p] = acc + b2d[p];
    }
  }
}

// ---------------- K6: fused_part[kc][b][p] = sum_{k in chunk} concat[b,k]*Wf[p,k]
// grid = 24 pb (128 p) * 16 kc (576 k) = 384 blocks; thread tile 4p x 4b
__global__ __launch_bounds__(256) void k6_fused(const float* __restrict__ Wf,
                                                const float* __restrict__ concatb,
                                                float* __restrict__ fpart) {
  int kc = blockIdx.x & 15, pb = blockIdx.x >> 4;
  __shared__ float wt[128 * 68];
  __shared__ float xt[32 * 68];
  int tid = threadIdx.x;
  int tp = tid & 31, tb = tid >> 5;  // tp: 0..31 (p = tp+32i), tb: 0..7 (b = tb+8j)
  float acc[4][4];
#pragma unroll
  for (int i = 0; i < 4; ++i)
#pragma unroll
    for (int j = 0; j < 4; ++j) acc[i][j] = 0.f;
  int kbase = kc * 576;
  for (int kt = 0; kt < 9; ++kt) {
    int k0 = kbase + kt * 64;
#pragma unroll
    for (int it = 0; it < 8; ++it) {  // 2048 float4 of Wf tile
      int i = tid + it * 256;
      int row = i >> 4, c4 = (i & 15) * 4;
      *(float4*)&wt[row * 68 + c4] =
          *(const float4*)&Wf[(size_t)(pb * 128 + row) * KFZ + k0 + c4];
    }
#pragma unroll
    for (int it = 0; it < 2; ++it) {  // 512 float4 of x tile
      int i = tid + it * 256;
      int row = i >> 4, c4 = (i & 15) * 4;
      *(float4*)&xt[row * 68 + c4] =
          *(const float4*)&concatb[(size_t)row * KFZ + k0 + c4];
    }
    __syncthreads();
#pragma unroll 4
    for (int kk = 0; kk < 64; kk += 4) {
      float4 wv[4], xv[4];
#pragma unroll
      for (int i = 0; i < 4; ++i) wv[i] = *(const float4*)&wt[(tp + 32 * i) * 68 + kk];
#pragma unroll
      for (int j = 0; j < 4; ++j) xv[j] = *(const float4*)&xt[(tb + 8 * j) * 68 + kk];
#pragma unroll
      for (int i = 0; i < 4; ++i)
#pragma unroll
        for (int j = 0; j < 4; ++j) {
          acc[i][j] = fmaf(wv[i].x, xv[j].x, acc[i][j]);
          acc[i][j] = fmaf(wv[i].y, xv[j].y, acc[i][j]);
          acc[i][j] = fmaf(wv[i].z, xv[j].z, acc[i][j]);
          acc[i][j] = fmaf(wv[i].w, xv[j].w, acc[i][j]);
        }
    }
    __syncthreads();
  }
#pragma unroll
  for (int i = 0; i < 4; ++i)
#pragma unroll
    for (int j = 0; j < 4; ++j)
      fpart[(size_t)(kc * NB + tb + 8 * j) * NP + pb * 128 + tp + 32 * i] = acc[i][j];
}

// ---------------- K7: out[b,s,p] = bf[p] + sum_kc fused_part[kc][b][p], broadcast over s
// grid 32 b * 3 pc * 4 sc = 384 blocks
__global__ __launch_bounds__(256) void k7_bcast(const float* __restrict__ fpart,
                                                const float* __restrict__ bfv,
                                                float* __restrict__ out) {
  int b = blockIdx.x & 31;
  int r = blockIdx.x >> 5;
  int pc = r % 3, sc = r / 3;
  int tid = threadIdx.x;
  int p4 = pc * 1024 + 4 * tid;
  float4 v = *(const float4*)&bfv[p4];
#pragma unroll
  for (int c = 0; c < 16; ++c) {
    float4 a = *(const float4*)&fpart[(size_t)(c * NB + b) * NP + p4];
    v.x += a.x; v.y += a.y; v.z += a.z; v.w += a.w;
  }
  float* obase = out + (size_t)b * NS * NP + p4;
  for (int ss = 0; ss < 64; ++ss) {
    int s = sc * 64 + ss;
    *(float4*)(obase + (size_t)s * NP) = v;
  }
}

extern "C" void kernel_launch(void* const* d_in, const int* in_sizes, int n_in,
                              void* d_out, int out_size, void* d_ws, size_t ws_size,
                              hipStream_t stream) {
  const float* f3d = (const float*)d_in[0];
  const float* f2d = (const float*)d_in[1];
  const float* ftx = (const float*)d_in[2];
  const float* W3d = (const float*)d_in[3];
  const float* b3d = (const float*)d_in[4];
  const float* W2d = (const float*)d_in[5];
  const float* b2d = (const float*)d_in[6];
  const float* Wf  = (const float*)d_in[7];
  const float* bfv = (const float*)d_in[8];
  float* out = (float*)d_out;
  float* ws = (float*)d_ws;

  // ws layout (floats)
  float* concatb = ws;                 // 32*9216      = 294912
  float* g_part  = ws + 294912;        // 32*32*768    = 786432
  float* w_s     = ws + 1081344;       // 32*256       = 8192
  float* p2f     = ws + 1089536;       // 32*768       = 24576
  float* w_t     = ws + 1114112;       // 32*512       = 16384
  float* ptp     = ws + 1130496;       // 4*32*3072    = 393216
  float* fpart   = ws + 1523712;       // 16*32*3072   = 1572864  (end 3096576 ~ 12.4 MB)

  k1_f3p<<<384, 256, 0, stream>>>(f3d, W3d, b3d, concatb);
  k2_gpart<<<96, 256, 0, stream>>>(W2d, concatb, g_part);
  k3a_scores<<<128, 256, 0, stream>>>(f2d, g_part, w_s);
  k_softmax<256><<<32, 256, 0, stream>>>(w_s);
  k3c_pool2f<<<96, 256, 0, stream>>>(f2d, w_s, p2f);
  k4a_scorest<<<256, 256, 0, stream>>>(ftx, concatb, w_t);
  k_softmax<512><<<32, 512, 0, stream>>>(w_t);
  k4c_poolt<<<384, 256, 0, stream>>>(ftx, w_t, ptp);
  k4d_red<<<384, 256, 0, stream>>>(ptp, concatb);
  k5_pool2d<<<384, 256, 0, stream>>>(W2d, b2d, p2f, concatb);
  k6_fused<<<384, 256, 0, stream>>>(Wf, concatb, fpart);
  k7_bcast<<<384, 256, 0, stream>>>(fpart, bfv, out);
}

// Round 2
// 553.118 us; speedup vs baseline: 1.1097x; 1.1097x over previous
//
#include <hip/hip_runtime.h>

#define NB 32
#define NS 256
#define NT 512
#define KD3 256
#define KD2 768
#define NP 3072
#define KFZ 9216

__device__ __forceinline__ float wave_red_sum(float v) {
#pragma unroll
  for (int o = 32; o; o >>= 1) v += __shfl_xor(v, o, 64);
  return v;
}
__device__ __forceinline__ float wave_red_max(float v) {
#pragma unroll
  for (int o = 32; o; o >>= 1) v = fmaxf(v, __shfl_xor(v, o, 64));
  return v;
}

// ---------------- L1: f3p[b,p] -> concat0[b][0:3072]; zero concat1..3 first third
__global__ __launch_bounds__(256) void k1_f3p(const float* __restrict__ f3d,
                                              const float* __restrict__ W3d,
                                              const float* __restrict__ b3d,
                                              float* __restrict__ c0, float* __restrict__ c1,
                                              float* __restrict__ c2, float* __restrict__ c3) {
  int b = blockIdx.x & 31, pc = blockIdx.x >> 5;  // 32 b x 12 pc
  __shared__ float4 xs[KD3 / 4];
  int tid = threadIdx.x;
  if (tid < KD3 / 4) xs[tid] = ((const float4*)(f3d + b * KD3))[tid];
  __syncthreads();
  int p = pc * 256 + tid;
  const float4* wrow = (const float4*)(W3d + (size_t)p * KD3);
  float acc = b3d[p];
#pragma unroll 8
  for (int i = 0; i < KD3 / 4; ++i) {
    float4 w = wrow[i], x = xs[i];
    acc = fmaf(w.x, x.x, acc); acc = fmaf(w.y, x.y, acc);
    acc = fmaf(w.z, x.z, acc); acc = fmaf(w.w, x.w, acc);
  }
  size_t o = (size_t)b * KFZ + p;
  c0[o] = acc; c1[o] = 0.f; c2[o] = 0.f; c3[o] = 0.f;
}

// ---------------- L2 merged: blocks [0,512) = online text pooling partials;
//                  blocks [512,608) = g_part = W2d^T f3p partials
__global__ __launch_bounds__(256) void k_L2(const float* __restrict__ ftx,
                                            const float* __restrict__ W2d,
                                            const float* __restrict__ c0,
                                            float* __restrict__ g_part,
                                            float* __restrict__ Pt,
                                            float* __restrict__ ml) {
  __shared__ float4 smem4[768];  // 12 KB, used by both branches
  float* sm = (float*)smem4;
  int tid = threadIdx.x;
  if (blockIdx.x < 512) {
    // online-softmax text pooling: wave-autonomous, 8 rows/wave
    int b = blockIdx.x & 31, tch = blockIdx.x >> 5;  // tch 0..15
    for (int i = tid; i < NP / 4; i += 256)
      smem4[i] = ((const float4*)(c0 + (size_t)b * KFZ))[i];
    __syncthreads();
    int wave = tid >> 6, lane = tid & 63;
    int t0 = tch * 32 + wave * 8;
    float m = -3.0e38f, l = 0.f;
    float4 acc[12];
#pragma unroll
    for (int j = 0; j < 12; ++j) acc[j] = make_float4(0.f, 0.f, 0.f, 0.f);
    for (int r = 0; r < 8; ++r) {
      const float4* row = (const float4*)(ftx + ((size_t)(b * NT + t0 + r)) * NP);
      float4 xr[12];
#pragma unroll
      for (int j = 0; j < 12; ++j) xr[j] = row[lane + 64 * j];
      float s = 0.f;
#pragma unroll
      for (int j = 0; j < 12; ++j) {
        float4 f = smem4[lane + 64 * j];
        s = fmaf(xr[j].x, f.x, s); s = fmaf(xr[j].y, f.y, s);
        s = fmaf(xr[j].z, f.z, s); s = fmaf(xr[j].w, f.w, s);
      }
      s = wave_red_sum(s);
      float mn = fmaxf(m, s);
      float al = __expf(m - mn);
      float e = __expf(s - mn);
      l = fmaf(l, al, e);
#pragma unroll
      for (int j = 0; j < 12; ++j) {
        acc[j].x = fmaf(acc[j].x, al, e * xr[j].x);
        acc[j].y = fmaf(acc[j].y, al, e * xr[j].y);
        acc[j].z = fmaf(acc[j].z, al, e * xr[j].z);
        acc[j].w = fmaf(acc[j].w, al, e * xr[j].w);
      }
      m = mn;
    }
    int c = tch * 4 + wave;  // 0..63
    float4* Pr = (float4*)(Pt + (size_t)(c * NB + b) * NP);
#pragma unroll
    for (int j = 0; j < 12; ++j) Pr[lane + 64 * j] = acc[j];
    if (lane == 0) { ml[(c * NB + b) * 2] = m; ml[(c * NB + b) * 2 + 1] = l; }
  } else {
    int id = blockIdx.x - 512;
    int dc = id % 3, kc = id / 3;  // 3 dc x 32 kc
    int p0 = kc * 96;
    for (int i = tid; i < NB * 96; i += 256) {
      int bb = i / 96, pp = i - bb * 96;
      sm[i] = c0[(size_t)bb * KFZ + p0 + pp];
    }
    __syncthreads();
    int d = dc * 256 + tid;
    float acc[NB];
#pragma unroll
    for (int b = 0; b < NB; ++b) acc[b] = 0.f;
    for (int pp = 0; pp < 96; pp += 4) {
      float w0 = W2d[(size_t)(p0 + pp + 0) * KD2 + d];
      float w1 = W2d[(size_t)(p0 + pp + 1) * KD2 + d];
      float w2 = W2d[(size_t)(p0 + pp + 2) * KD2 + d];
      float w3 = W2d[(size_t)(p0 + pp + 3) * KD2 + d];
#pragma unroll
      for (int b = 0; b < NB; ++b) {
        float4 x4 = *(const float4*)&sm[b * 96 + pp];
        acc[b] = fmaf(w0, x4.x, acc[b]); acc[b] = fmaf(w1, x4.y, acc[b]);
        acc[b] = fmaf(w2, x4.z, acc[b]); acc[b] = fmaf(w3, x4.w, acc[b]);
      }
    }
#pragma unroll
    for (int b = 0; b < NB; ++b) g_part[(size_t)(kc * NB + b) * KD2 + d] = acc[b];
  }
}

// ---------------- L3 merged: blocks [0,128) = scores_s (raw); [128,224) = text combine
__global__ __launch_bounds__(256) void k_L3(const float* __restrict__ f2d,
                                            const float* __restrict__ g_part,
                                            float* __restrict__ sraw,
                                            const float* __restrict__ Pt,
                                            const float* __restrict__ ml,
                                            float* __restrict__ c0, float* __restrict__ c1,
                                            float* __restrict__ c2, float* __restrict__ c3) {
  __shared__ float4 sh4[KD2 / 4];  // 768 floats
  float* sh = (float*)sh4;
  int tid = threadIdx.x;
  if (blockIdx.x < 128) {
    int b = blockIdx.x & 31, sc = blockIdx.x >> 5;
    for (int i = tid; i < KD2; i += 256) {
      float a = 0.f;
      for (int c = 0; c < 32; ++c) a += g_part[(size_t)(c * NB + b) * KD2 + i];
      sh[i] = a;
    }
    __syncthreads();
    int wave = tid >> 6, lane = tid & 63;
    for (int i = 0; i < 16; ++i) {
      int s = sc * 64 + wave * 16 + i;
      const float4* row = (const float4*)(f2d + ((size_t)b * NS + s) * KD2);
      float acc = 0.f;
#pragma unroll
      for (int j = 0; j < 3; ++j) {
        float4 v = row[lane + 64 * j];
        float4 g = sh4[lane + 64 * j];
        acc = fmaf(v.x, g.x, acc); acc = fmaf(v.y, g.y, acc);
        acc = fmaf(v.z, g.z, acc); acc = fmaf(v.w, g.w, acc);
      }
      acc = wave_red_sum(acc);
      if (lane == 0) sraw[b * NS + s] = acc;
    }
  } else {
    int id = blockIdx.x - 128;
    int b = id & 31, pc = id >> 5;  // pc 0..2
    if (tid < 64) {
      sh[2 * tid] = ml[(tid * NB + b) * 2];
      sh[2 * tid + 1] = ml[(tid * NB + b) * 2 + 1];
    }
    __syncthreads();
    float M = -3.0e38f;
    for (int c = 0; c < 64; ++c) M = fmaxf(M, sh[2 * c]);
    float denom = 0.f;
    for (int c = 0; c < 64; ++c) denom += __expf(sh[2 * c] - M) * sh[2 * c + 1];
    float inv = 1.f / denom;
    int p4 = pc * 1024 + tid * 4;
    float4 a = make_float4(0.f, 0.f, 0.f, 0.f);
    for (int c = 0; c < 64; ++c) {
      float w = __expf(sh[2 * c] - M);
      float4 v = *(const float4*)&Pt[(size_t)(c * NB + b) * NP + p4];
      a.x = fmaf(w, v.x, a.x); a.y = fmaf(w, v.y, a.y);
      a.z = fmaf(w, v.z, a.z); a.w = fmaf(w, v.w, a.w);
    }
    a.x *= inv; a.y *= inv; a.z *= inv; a.w *= inv;
    size_t o = (size_t)b * KFZ + 2 * NP + p4;
    float4 z = make_float4(0.f, 0.f, 0.f, 0.f);
    *(float4*)&c0[o] = a;
    *(float4*)&c1[o] = z; *(float4*)&c2[o] = z; *(float4*)&c3[o] = z;
  }
}

// ---------------- L4: in-block softmax_s + partial f2d pooling
// grid 192 = 32 b x 3 dc x 2 sc
__global__ __launch_bounds__(256) void k3c_sm(const float* __restrict__ f2d,
                                              const float* __restrict__ sraw,
                                              float* __restrict__ p2f) {
  int b = blockIdx.x & 31;
  int r = blockIdx.x >> 5;
  int dc = r % 3, sc = r / 3;
  __shared__ float pr[NS];
  __shared__ float red[8];
  int tid = threadIdx.x;
  int wave = tid >> 6, lane = tid & 63;
  float v = sraw[b * NS + tid];
  float mx = wave_red_max(v);
  if (lane == 0) red[wave] = mx;
  __syncthreads();
  float M = fmaxf(fmaxf(red[0], red[1]), fmaxf(red[2], red[3]));
  float e = __expf(v - M);
  pr[tid] = e;
  float smv = wave_red_sum(e);
  if (lane == 0) red[4 + wave] = smv;
  __syncthreads();
  float inv = 1.f / (red[4] + red[5] + red[6] + red[7]);
  int d = dc * 256 + tid;
  float acc = 0.f;
  const float* base = f2d + ((size_t)b * NS + sc * 128) * KD2 + d;
#pragma unroll 8
  for (int s = 0; s < 128; ++s)
    acc = fmaf(pr[sc * 128 + s], base[(size_t)s * KD2], acc);
  p2f[(size_t)(sc * NB + b) * KD2 + d] = acc * inv;
}

// ---------------- L5: pooled_2d = p2f @ W2d^T + b2d, k-split 4 into concat0..3
// grid 192 = 48 pb (64 p) x 4 ks (192 d); block tile 64p x 32b, thread 2p x 4b
__global__ __launch_bounds__(256) void k5_pool2d(const float* __restrict__ W2d,
                                                 const float* __restrict__ b2d,
                                                 const float* __restrict__ p2f,
                                                 float* __restrict__ c0, float* __restrict__ c1,
                                                 float* __restrict__ c2, float* __restrict__ c3) {
  int pb = blockIdx.x >> 2, ks = blockIdx.x & 3;
  __shared__ __align__(16) float wt[64 * 68];
  __shared__ __align__(16) float xt[32 * 68];
  int tid = threadIdx.x;
  int tp = tid & 31, tb = tid >> 5;  // p = pb*64 + tp + 32i; b = tb + 8j
  float acc[2][4];
#pragma unroll
  for (int i = 0; i < 2; ++i)
#pragma unroll
    for (int j = 0; j < 4; ++j) acc[i][j] = 0.f;
  for (int dk = 0; dk < 3; ++dk) {
    int d0 = ks * 192 + dk * 64;
#pragma unroll
    for (int it = 0; it < 4; ++it) {  // wt: 1024 float4
      int idx = tid + it * 256;
      int row = idx >> 4, c4 = (idx & 15) * 4;
      *(float4*)&wt[row * 68 + c4] =
          *(const float4*)&W2d[(size_t)(pb * 64 + row) * KD2 + d0 + c4];
    }
#pragma unroll
    for (int it = 0; it < 2; ++it) {  // xt: 512 float4, sum of 2 s-partials
      int idx = tid + it * 256;
      int row = idx >> 4, c4 = (idx & 15) * 4;
      float4 a = *(const float4*)&p2f[(size_t)row * KD2 + d0 + c4];
      float4 bq = *(const float4*)&p2f[(size_t)(NB + row) * KD2 + d0 + c4];
      a.x += bq.x; a.y += bq.y; a.z += bq.z; a.w += bq.w;
      *(float4*)&xt[row * 68 + c4] = a;
    }
    __syncthreads();
#pragma unroll 4
    for (int kk = 0; kk < 64; kk += 4) {
      float4 wv[2], xv[4];
#pragma unroll
      for (int i = 0; i < 2; ++i) wv[i] = *(const float4*)&wt[(tp + 32 * i) * 68 + kk];
#pragma unroll
      for (int j = 0; j < 4; ++j) xv[j] = *(const float4*)&xt[(tb + 8 * j) * 68 + kk];
#pragma unroll
      for (int i = 0; i < 2; ++i)
#pragma unroll
        for (int j = 0; j < 4; ++j) {
          acc[i][j] = fmaf(wv[i].x, xv[j].x, acc[i][j]);
          acc[i][j] = fmaf(wv[i].y, xv[j].y, acc[i][j]);
          acc[i][j] = fmaf(wv[i].z, xv[j].z, acc[i][j]);
          acc[i][j] = fmaf(wv[i].w, xv[j].w, acc[i][j]);
        }
    }
    __syncthreads();
  }
  float* dst = (ks == 0) ? c0 : (ks == 1) ? c1 : (ks == 2) ? c2 : c3;
#pragma unroll
  for (int i = 0; i < 2; ++i) {
    int p = pb * 64 + tp + 32 * i;
    float bias = (ks == 0) ? b2d[p] : 0.f;
#pragma unroll
    for (int j = 0; j < 4; ++j)
      dst[(size_t)(tb + 8 * j) * KFZ + NP + p] = acc[i][j] + bias;
  }
}

// ---------------- L6: fused partial GEMM: fpart[kc][b][p] over 576-k chunks
// grid 256 = 16 pb (192 p) x 16 kc; block tile 192p x 32b, thread 6p x 4b
__global__ __launch_bounds__(256) void k6_fused(const float* __restrict__ Wf,
                                                const float* __restrict__ c0,
                                                const float* __restrict__ c1,
                                                const float* __restrict__ c2,
                                                const float* __restrict__ c3,
                                                float* __restrict__ fpart) {
  int pb = blockIdx.x >> 4, kc = blockIdx.x & 15;
  __shared__ __align__(16) float wt[192 * 68];  // 52.2 KB
  __shared__ __align__(16) float xt[32 * 68];   // 8.7 KB
  int tid = threadIdx.x;
  int tp = tid & 31, tb = tid >> 5;  // p = pb*192 + tp + 32i (i<6); b = tb + 8j (j<4)
  float acc[6][4];
#pragma unroll
  for (int i = 0; i < 6; ++i)
#pragma unroll
    for (int j = 0; j < 4; ++j) acc[i][j] = 0.f;
  for (int kt = 0; kt < 9; ++kt) {
    int k0 = kc * 576 + kt * 64;
#pragma unroll
    for (int it = 0; it < 12; ++it) {  // wt: 3072 float4
      int idx = tid + it * 256;
      int row = idx >> 4, c4 = (idx & 15) * 4;
      *(float4*)&wt[row * 68 + c4] =
          *(const float4*)&Wf[(size_t)(pb * 192 + row) * KFZ + k0 + c4];
    }
#pragma unroll
    for (int it = 0; it < 2; ++it) {  // xt: 512 float4, sum of 4 concat partials
      int idx = tid + it * 256;
      int row = idx >> 4, c4 = (idx & 15) * 4;
      size_t o = (size_t)row * KFZ + k0 + c4;
      float4 a = *(const float4*)&c0[o];
      float4 v1 = *(const float4*)&c1[o];
      float4 v2 = *(const float4*)&c2[o];
      float4 v3 = *(const float4*)&c3[o];
      a.x += v1.x + v2.x + v3.x; a.y += v1.y + v2.y + v3.y;
      a.z += v1.z + v2.z + v3.z; a.w += v1.w + v2.w + v3.w;
      *(float4*)&xt[row * 68 + c4] = a;
    }
    __syncthreads();
#pragma unroll 4
    for (int kk = 0; kk < 64; kk += 4) {
      float4 wv[6], xv[4];
#pragma unroll
      for (int i = 0; i < 6; ++i) wv[i] = *(const float4*)&wt[(tp + 32 * i) * 68 + kk];
#pragma unroll
      for (int j = 0; j < 4; ++j) xv[j] = *(const float4*)&xt[(tb + 8 * j) * 68 + kk];
#pragma unroll
      for (int i = 0; i < 6; ++i)
#pragma unroll
        for (int j = 0; j < 4; ++j) {
          acc[i][j] = fmaf(wv[i].x, xv[j].x, acc[i][j]);
          acc[i][j] = fmaf(wv[i].y, xv[j].y, acc[i][j]);
          acc[i][j] = fmaf(wv[i].z, xv[j].z, acc[i][j]);
          acc[i][j] = fmaf(wv[i].w, xv[j].w, acc[i][j]);
        }
    }
    __syncthreads();
  }
#pragma unroll
  for (int i = 0; i < 6; ++i)
#pragma unroll
    for (int j = 0; j < 4; ++j)
      fpart[(size_t)(kc * NB + tb + 8 * j) * NP + pb * 192 + tp + 32 * i] = acc[i][j];
}

// ---------------- L7: out[b,s,p] = bf[p] + sum_kc fpart, broadcast over s
// grid 384 = 32 b x 3 pc x 4 sc
__global__ __launch_bounds__(256) void k7_bcast(const float* __restrict__ fpart,
                                                const float* __restrict__ bfv,
                                                float* __restrict__ out) {
  int b = blockIdx.x & 31;
  int r = blockIdx.x >> 5;
  int pc = r % 3, sc = r / 3;
  int tid = threadIdx.x;
  int p4 = pc * 1024 + 4 * tid;
  float4 v = *(const float4*)&bfv[p4];
#pragma unroll
  for (int c = 0; c < 16; ++c) {
    float4 a = *(const float4*)&fpart[(size_t)(c * NB + b) * NP + p4];
    v.x += a.x; v.y += a.y; v.z += a.z; v.w += a.w;
  }
  float* obase = out + (size_t)b * NS * NP + p4;
  for (int ss = 0; ss < 64; ++ss) {
    int s = sc * 64 + ss;
    *(float4*)(obase + (size_t)s * NP) = v;
  }
}

extern "C" void kernel_launch(void* const* d_in, const int* in_sizes, int n_in,
                              void* d_out, int out_size, void* d_ws, size_t ws_size,
                              hipStream_t stream) {
  const float* f3d = (const float*)d_in[0];
  const float* f2d = (const float*)d_in[1];
  const float* ftx = (const float*)d_in[2];
  const float* W3d = (const float*)d_in[3];
  const float* b3d = (const float*)d_in[4];
  const float* W2d = (const float*)d_in[5];
  const float* b2d = (const float*)d_in[6];
  const float* Wf  = (const float*)d_in[7];
  const float* bfv = (const float*)d_in[8];
  float* out = (float*)d_out;
  float* ws = (float*)d_ws;

  // ws layout (floats)
  float* c0     = ws;                  // 294912
  float* c1     = ws + 294912;
  float* c2     = ws + 589824;
  float* c3     = ws + 884736;
  float* g_part = ws + 1179648;        // 32*32*768 = 786432
  float* sraw   = ws + 1966080;        // 8192
  float* p2f    = ws + 1974272;        // 2*32*768 = 49152
  float* ml     = ws + 2023424;        // 64*32*2 = 4096
  float* Pt     = ws + 2027520;        // 64*32*3072 = 6291456
  float* fpart  = ws + 8318976;        // 16*32*3072 = 1572864 (end ~39.6 MB)

  k1_f3p<<<384, 256, 0, stream>>>(f3d, W3d, b3d, c0, c1, c2, c3);
  k_L2<<<608, 256, 0, stream>>>(ftx, W2d, c0, g_part, Pt, ml);
  k_L3<<<224, 256, 0, stream>>>(f2d, g_part, sraw, Pt, ml, c0, c1, c2, c3);
  k3c_sm<<<192, 256, 0, stream>>>(f2d, sraw, p2f);
  k5_pool2d<<<192, 256, 0, stream>>>(W2d, b2d, p2f, c0, c1, c2, c3);
  k6_fused<<<256, 256, 0, stream>>>(Wf, c0, c1, c2, c3, fpart);
  k7_bcast<<<384, 256, 0, stream>>>(fpart, bfv, out);
}

// Round 3
// 540.734 us; speedup vs baseline: 1.1351x; 1.0229x over previous
//
#include <hip/hip_runtime.h>

#define NB 32
#define NS 256
#define NT 512
#define KD3 256
#define KD2 768
#define NP 3072
#define KFZ 9216

__device__ __forceinline__ float wave_red_sum(float v) {
#pragma unroll
  for (int o = 32; o; o >>= 1) v += __shfl_xor(v, o, 64);
  return v;
}
__device__ __forceinline__ float wave_red_max(float v) {
#pragma unroll
  for (int o = 32; o; o >>= 1) v = fmaxf(v, __shfl_xor(v, o, 64));
  return v;
}

// ---------------- k1: f3p[b,p] -> c0[b][0:NP]; zero same range of c1..c3
__global__ __launch_bounds__(256) void k1_f3p(const float* __restrict__ f3d,
                                              const float* __restrict__ W3d,
                                              const float* __restrict__ b3d,
                                              float* __restrict__ c0, float* __restrict__ c1,
                                              float* __restrict__ c2, float* __restrict__ c3) {
  int b = blockIdx.x & 31, pc = blockIdx.x >> 5;  // 32 b x 12 pc
  __shared__ float4 xs[KD3 / 4];
  int tid = threadIdx.x;
  if (tid < KD3 / 4) xs[tid] = ((const float4*)(f3d + b * KD3))[tid];
  __syncthreads();
  int p = pc * 256 + tid;
  const float4* wrow = (const float4*)(W3d + (size_t)p * KD3);
  float acc = b3d[p];
#pragma unroll 8
  for (int i = 0; i < KD3 / 4; ++i) {
    float4 w = wrow[i], x = xs[i];
    acc = fmaf(w.x, x.x, acc); acc = fmaf(w.y, x.y, acc);
    acc = fmaf(w.z, x.z, acc); acc = fmaf(w.w, x.w, acc);
  }
  size_t o = (size_t)b * KFZ + p;
  c0[o] = acc; c1[o] = 0.f; c2[o] = 0.f; c3[o] = 0.f;
}

// ---------------- kT: online-softmax text pooling, explicit 2-row pipeline
// grid 512 = 32 b x 16 tch; wave handles 8 rows; partials Pt[c][b][p], ml[c][b]
__global__ __launch_bounds__(256, 2) void kT_text(const float* __restrict__ ftx,
                                                  const float* __restrict__ c0,
                                                  float* __restrict__ Pt,
                                                  float* __restrict__ ml) {
  int b = blockIdx.x & 31, tch = blockIdx.x >> 5;
  __shared__ float4 f4[NP / 4];
  int tid = threadIdx.x;
#pragma unroll
  for (int i = 0; i < 3; ++i)
    f4[tid + 256 * i] = ((const float4*)(c0 + (size_t)b * KFZ))[tid + 256 * i];
  __syncthreads();
  int wave = tid >> 6, lane = tid & 63;
  int t0 = tch * 32 + wave * 8;
  const float4* rbase = (const float4*)(ftx + ((size_t)(b * NT + t0)) * NP);
  float4 xa[12], xb[12];
#pragma unroll
  for (int j = 0; j < 12; ++j) xa[j] = rbase[lane + 64 * j];
  float m = -3.0e38f, l = 0.f;
  float4 acc[12];
#pragma unroll
  for (int j = 0; j < 12; ++j) acc[j] = make_float4(0.f, 0.f, 0.f, 0.f);
#pragma unroll
  for (int r = 0; r < 8; ++r) {
    float4* cur = (r & 1) ? xb : xa;
    float4* nxt = (r & 1) ? xa : xb;
    if (r < 7) {
      const float4* rn = rbase + (size_t)(r + 1) * (NP / 4);
#pragma unroll
      for (int j = 0; j < 12; ++j) nxt[j] = rn[lane + 64 * j];
    }
    float sx = 0.f, sy = 0.f, sz = 0.f, sw = 0.f;
#pragma unroll
    for (int j = 0; j < 12; ++j) {
      float4 f = f4[lane + 64 * j];
      sx = fmaf(cur[j].x, f.x, sx); sy = fmaf(cur[j].y, f.y, sy);
      sz = fmaf(cur[j].z, f.z, sz); sw = fmaf(cur[j].w, f.w, sw);
    }
    float s = (sx + sy) + (sz + sw);
    s = wave_red_sum(s);
    float mn = fmaxf(m, s);
    float al = __expf(m - mn);
    float e = __expf(s - mn);
    l = fmaf(l, al, e);
#pragma unroll
    for (int j = 0; j < 12; ++j) {
      acc[j].x = fmaf(acc[j].x, al, e * cur[j].x);
      acc[j].y = fmaf(acc[j].y, al, e * cur[j].y);
      acc[j].z = fmaf(acc[j].z, al, e * cur[j].z);
      acc[j].w = fmaf(acc[j].w, al, e * cur[j].w);
    }
    m = mn;
  }
  int c = tch * 4 + wave;
  float4* Pr = (float4*)(Pt + (size_t)(c * NB + b) * NP);
#pragma unroll
  for (int j = 0; j < 12; ++j) Pr[lane + 64 * j] = acc[j];
  if (lane == 0) { ml[(c * NB + b) * 2] = m; ml[(c * NB + b) * 2 + 1] = l; }
}

// ---------------- k2: g_part[kc][b][d] = sum_{p chunk} W2d[p,d]*f3p[b,p]; 96 blocks
__global__ __launch_bounds__(256) void k2_gpart(const float* __restrict__ W2d,
                                                const float* __restrict__ c0,
                                                float* __restrict__ g_part) {
  int dc = blockIdx.x % 3, kc = blockIdx.x / 3;
  __shared__ float xs[NB * 96];
  int tid = threadIdx.x;
  int p0 = kc * 96;
  for (int i = tid; i < NB * 96; i += 256) {
    int bb = i / 96, pp = i - bb * 96;
    xs[i] = c0[(size_t)bb * KFZ + p0 + pp];
  }
  __syncthreads();
  int d = dc * 256 + tid;
  float acc[NB];
#pragma unroll
  for (int b = 0; b < NB; ++b) acc[b] = 0.f;
  for (int pp = 0; pp < 96; pp += 8) {
    float w[8];
#pragma unroll
    for (int u = 0; u < 8; ++u) w[u] = W2d[(size_t)(p0 + pp + u) * KD2 + d];
#pragma unroll
    for (int b = 0; b < NB; ++b) {
      float4 x0 = *(const float4*)&xs[b * 96 + pp];
      float4 x1 = *(const float4*)&xs[b * 96 + pp + 4];
      acc[b] = fmaf(w[0], x0.x, acc[b]); acc[b] = fmaf(w[1], x0.y, acc[b]);
      acc[b] = fmaf(w[2], x0.z, acc[b]); acc[b] = fmaf(w[3], x0.w, acc[b]);
      acc[b] = fmaf(w[4], x1.x, acc[b]); acc[b] = fmaf(w[5], x1.y, acc[b]);
      acc[b] = fmaf(w[6], x1.z, acc[b]); acc[b] = fmaf(w[7], x1.w, acc[b]);
    }
  }
#pragma unroll
  for (int b = 0; b < NB; ++b) g_part[(size_t)(kc * NB + b) * KD2 + d] = acc[b];
}

// ---------------- k3a: scores_s raw; grid 256 = 32 b x 8 sc; wave: 8 rows in 2 groups of 4
__global__ __launch_bounds__(256) void k3a_scores(const float* __restrict__ f2d,
                                                  const float* __restrict__ g_part,
                                                  float* __restrict__ sraw) {
  int b = blockIdx.x & 31, sc = blockIdx.x >> 5;
  __shared__ float4 g4[KD2 / 4];
  float* g = (float*)g4;
  int tid = threadIdx.x;
  for (int i = tid; i < KD2; i += 256) {
    float a = 0.f;
#pragma unroll 8
    for (int c = 0; c < 32; ++c) a += g_part[(size_t)(c * NB + b) * KD2 + i];
    g[i] = a;
  }
  __syncthreads();
  int wave = tid >> 6, lane = tid & 63;
#pragma unroll
  for (int grp = 0; grp < 2; ++grp) {
    int s0 = sc * 32 + wave * 8 + grp * 4;
    float4 x[4][3];
#pragma unroll
    for (int rr = 0; rr < 4; ++rr) {
      const float4* row = (const float4*)(f2d + ((size_t)b * NS + s0 + rr) * KD2);
#pragma unroll
      for (int j = 0; j < 3; ++j) x[rr][j] = row[lane + 64 * j];
    }
#pragma unroll
    for (int rr = 0; rr < 4; ++rr) {
      float acc = 0.f;
#pragma unroll
      for (int j = 0; j < 3; ++j) {
        float4 f = g4[lane + 64 * j];
        acc = fmaf(x[rr][j].x, f.x, acc); acc = fmaf(x[rr][j].y, f.y, acc);
        acc = fmaf(x[rr][j].z, f.z, acc); acc = fmaf(x[rr][j].w, f.w, acc);
      }
      acc = wave_red_sum(acc);
      if (lane == 0) sraw[b * NS + s0 + rr] = acc;
    }
  }
}

// ---------------- kComb: combine 64 text partials -> c0[b][2NP..3NP); zero c1..c3
// grid 96 = 32 b x 3 pc
__global__ __launch_bounds__(256) void kComb(const float* __restrict__ Pt,
                                             const float* __restrict__ ml,
                                             float* __restrict__ c0, float* __restrict__ c1,
                                             float* __restrict__ c2, float* __restrict__ c3) {
  int b = blockIdx.x & 31, pc = blockIdx.x >> 5;
  __shared__ float sm[128];
  int tid = threadIdx.x;
  if (tid < 64) {
    sm[tid] = ml[(tid * NB + b) * 2];
    sm[64 + tid] = ml[(tid * NB + b) * 2 + 1];
  }
  __syncthreads();
  float M = -3.0e38f;
#pragma unroll 8
  for (int c = 0; c < 64; ++c) M = fmaxf(M, sm[c]);
  float denom = 0.f;
#pragma unroll 8
  for (int c = 0; c < 64; ++c) denom += __expf(sm[c] - M) * sm[64 + c];
  float inv = 1.f / denom;
  int p4 = pc * 1024 + tid * 4;
  float4 a = make_float4(0.f, 0.f, 0.f, 0.f);
#pragma unroll 2
  for (int cg = 0; cg < 8; ++cg) {
    float4 v[8];
#pragma unroll
    for (int u = 0; u < 8; ++u)
      v[u] = *(const float4*)&Pt[(size_t)((cg * 8 + u) * NB + b) * NP + p4];
#pragma unroll
    for (int u = 0; u < 8; ++u) {
      float w = __expf(sm[cg * 8 + u] - M);
      a.x = fmaf(w, v[u].x, a.x); a.y = fmaf(w, v[u].y, a.y);
      a.z = fmaf(w, v[u].z, a.z); a.w = fmaf(w, v[u].w, a.w);
    }
  }
  a.x *= inv; a.y *= inv; a.z *= inv; a.w *= inv;
  size_t o = (size_t)b * KFZ + 2 * NP + p4;
  float4 z = make_float4(0.f, 0.f, 0.f, 0.f);
  *(float4*)&c0[o] = a;
  *(float4*)&c1[o] = z; *(float4*)&c2[o] = z; *(float4*)&c3[o] = z;
}

// ---------------- k3c: softmax_s + partial f2d pooling; grid 384 = 32 b x 3 dc x 4 sc
__global__ __launch_bounds__(256) void k3c_sm(const float* __restrict__ f2d,
                                              const float* __restrict__ sraw,
                                              float* __restrict__ p2f) {
  int b = blockIdx.x & 31;
  int r = blockIdx.x >> 5;
  int dc = r % 3, sc = r / 3;
  __shared__ float pr[NS];
  __shared__ float red[8];
  int tid = threadIdx.x;
  int wave = tid >> 6, lane = tid & 63;
  float v = sraw[b * NS + tid];
  float mx = wave_red_max(v);
  if (lane == 0) red[wave] = mx;
  __syncthreads();
  float M = fmaxf(fmaxf(red[0], red[1]), fmaxf(red[2], red[3]));
  float e = __expf(v - M);
  pr[tid] = e;
  float smv = wave_red_sum(e);
  if (lane == 0) red[4 + wave] = smv;
  __syncthreads();
  float inv = 1.f / (red[4] + red[5] + red[6] + red[7]);
  int d = dc * 256 + tid;
  float acc = 0.f;
  const float* base = f2d + ((size_t)b * NS + sc * 64) * KD2 + d;
#pragma unroll 2
  for (int sg = 0; sg < 8; ++sg) {
    float xv[8];
#pragma unroll
    for (int u = 0; u < 8; ++u) xv[u] = base[(size_t)(sg * 8 + u) * KD2];
#pragma unroll
    for (int u = 0; u < 8; ++u) acc = fmaf(pr[sc * 64 + sg * 8 + u], xv[u], acc);
  }
  p2f[(size_t)(sc * NB + b) * KD2 + d] = acc * inv;
}

// ---------------- k5: pooled_2d = (sum of 4 p2f partials) @ W2d^T + b2d, k-split 4
// grid 192 = 48 pb x 4 ks
__global__ __launch_bounds__(256) void k5_pool2d(const float* __restrict__ W2d,
                                                 const float* __restrict__ b2d,
                                                 const float* __restrict__ p2f,
                                                 float* __restrict__ c0, float* __restrict__ c1,
                                                 float* __restrict__ c2, float* __restrict__ c3) {
  int pb = blockIdx.x >> 2, ks = blockIdx.x & 3;
  __shared__ __align__(16) float wt[64 * 68];
  __shared__ __align__(16) float xt[32 * 68];
  int tid = threadIdx.x;
  int tp = tid & 31, tb = tid >> 5;
  float acc[2][4];
#pragma unroll
  for (int i = 0; i < 2; ++i)
#pragma unroll
    for (int j = 0; j < 4; ++j) acc[i][j] = 0.f;
  for (int dk = 0; dk < 3; ++dk) {
    int d0 = ks * 192 + dk * 64;
#pragma unroll
    for (int it = 0; it < 4; ++it) {
      int idx = tid + it * 256;
      int row = idx >> 4, c4 = (idx & 15) * 4;
      *(float4*)&wt[row * 68 + c4] =
          *(const float4*)&W2d[(size_t)(pb * 64 + row) * KD2 + d0 + c4];
    }
#pragma unroll
    for (int it = 0; it < 2; ++it) {
      int idx = tid + it * 256;
      int row = idx >> 4, c4 = (idx & 15) * 4;
      float4 a = *(const float4*)&p2f[(size_t)row * KD2 + d0 + c4];
      float4 q1 = *(const float4*)&p2f[(size_t)(NB + row) * KD2 + d0 + c4];
      float4 q2 = *(const float4*)&p2f[(size_t)(2 * NB + row) * KD2 + d0 + c4];
      float4 q3 = *(const float4*)&p2f[(size_t)(3 * NB + row) * KD2 + d0 + c4];
      a.x += q1.x + q2.x + q3.x; a.y += q1.y + q2.y + q3.y;
      a.z += q1.z + q2.z + q3.z; a.w += q1.w + q2.w + q3.w;
      *(float4*)&xt[row * 68 + c4] = a;
    }
    __syncthreads();
#pragma unroll 4
    for (int kk = 0; kk < 64; kk += 4) {
      float4 wv[2], xv[4];
#pragma unroll
      for (int i = 0; i < 2; ++i) wv[i] = *(const float4*)&wt[(tp + 32 * i) * 68 + kk];
#pragma unroll
      for (int j = 0; j < 4; ++j) xv[j] = *(const float4*)&xt[(tb + 8 * j) * 68 + kk];
#pragma unroll
      for (int i = 0; i < 2; ++i)
#pragma unroll
        for (int j = 0; j < 4; ++j) {
          acc[i][j] = fmaf(wv[i].x, xv[j].x, acc[i][j]);
          acc[i][j] = fmaf(wv[i].y, xv[j].y, acc[i][j]);
          acc[i][j] = fmaf(wv[i].z, xv[j].z, acc[i][j]);
          acc[i][j] = fmaf(wv[i].w, xv[j].w, acc[i][j]);
        }
    }
    __syncthreads();
  }
  float* dst = (ks == 0) ? c0 : (ks == 1) ? c1 : (ks == 2) ? c2 : c3;
#pragma unroll
  for (int i = 0; i < 2; ++i) {
    int p = pb * 64 + tp + 32 * i;
    float bias = (ks == 0) ? b2d[p] : 0.f;
#pragma unroll
    for (int j = 0; j < 4; ++j)
      dst[(size_t)(tb + 8 * j) * KFZ + NP + p] = acc[i][j] + bias;
  }
}

// ---------------- k_csum: c0 += c1 + c2 + c3 (full concat); grid 288
__global__ __launch_bounds__(256) void k_csum(float* __restrict__ c0,
                                              const float* __restrict__ c1,
                                              const float* __restrict__ c2,
                                              const float* __restrict__ c3) {
  int i = blockIdx.x * 256 + threadIdx.x;
  float4 a = ((float4*)c0)[i];
  float4 v1 = ((const float4*)c1)[i];
  float4 v2 = ((const float4*)c2)[i];
  float4 v3 = ((const float4*)c3)[i];
  a.x += v1.x + v2.x + v3.x; a.y += v1.y + v2.y + v3.y;
  a.z += v1.z + v2.z + v3.z; a.w += v1.w + v2.w + v3.w;
  ((float4*)c0)[i] = a;
}

// ---------------- k6: fused partial GEMM; grid 512 = 32 pb (96 p) x 16 kc (576 k)
__global__ __launch_bounds__(256) void k6_fused(const float* __restrict__ Wf,
                                                const float* __restrict__ c0,
                                                float* __restrict__ fpart) {
  int pb = blockIdx.x >> 4, kc = blockIdx.x & 15;
  __shared__ __align__(16) float wt[96 * 68];  // 26.1 KB
  __shared__ __align__(16) float xt[32 * 68];  // 8.7 KB
  int tid = threadIdx.x;
  int tp = tid & 31, tb = tid >> 5;  // p = pb*96 + tp + 32i (i<3); b = tb + 8j (j<4)
  float acc[3][4];
#pragma unroll
  for (int i = 0; i < 3; ++i)
#pragma unroll
    for (int j = 0; j < 4; ++j) acc[i][j] = 0.f;
  for (int kt = 0; kt < 9; ++kt) {
    int k0 = kc * 576 + kt * 64;
#pragma unroll
    for (int it = 0; it < 6; ++it) {  // wt: 1536 float4
      int idx = tid + it * 256;
      int row = idx >> 4, c4 = (idx & 15) * 4;
      *(float4*)&wt[row * 68 + c4] =
          *(const float4*)&Wf[(size_t)(pb * 96 + row) * KFZ + k0 + c4];
    }
#pragma unroll
    for (int it = 0; it < 2; ++it) {  // xt: 512 float4
      int idx = tid + it * 256;
      int row = idx >> 4, c4 = (idx & 15) * 4;
      *(float4*)&xt[row * 68 + c4] =
          *(const float4*)&c0[(size_t)row * KFZ + k0 + c4];
    }
    __syncthreads();
#pragma unroll 4
    for (int kk = 0; kk < 64; kk += 4) {
      float4 wv[3], xv[4];
#pragma unroll
      for (int i = 0; i < 3; ++i) wv[i] = *(const float4*)&wt[(tp + 32 * i) * 68 + kk];
#pragma unroll
      for (int j = 0; j < 4; ++j) xv[j] = *(const float4*)&xt[(tb + 8 * j) * 68 + kk];
#pragma unroll
      for (int i = 0; i < 3; ++i)
#pragma unroll
        for (int j = 0; j < 4; ++j) {
          acc[i][j] = fmaf(wv[i].x, xv[j].x, acc[i][j]);
          acc[i][j] = fmaf(wv[i].y, xv[j].y, acc[i][j]);
          acc[i][j] = fmaf(wv[i].z, xv[j].z, acc[i][j]);
          acc[i][j] = fmaf(wv[i].w, xv[j].w, acc[i][j]);
        }
    }
    __syncthreads();
  }
#pragma unroll
  for (int i = 0; i < 3; ++i)
#pragma unroll
    for (int j = 0; j < 4; ++j)
      fpart[(size_t)(kc * NB + tb + 8 * j) * NP + pb * 96 + tp + 32 * i] = acc[i][j];
}

// ---------------- k7: out = bf + sum_kc fpart, broadcast over s; grid 768
__global__ __launch_bounds__(256) void k7_bcast(const float* __restrict__ fpart,
                                                const float* __restrict__ bfv,
                                                float* __restrict__ out) {
  int b = blockIdx.x & 31;
  int r = blockIdx.x >> 5;
  int pc = r % 3, sc = r / 3;  // pc<3, sc<8
  int tid = threadIdx.x;
  int p4 = pc * 1024 + 4 * tid;
  float4 v = *(const float4*)&bfv[p4];
#pragma unroll
  for (int c = 0; c < 16; ++c) {
    float4 a = *(const float4*)&fpart[(size_t)(c * NB + b) * NP + p4];
    v.x += a.x; v.y += a.y; v.z += a.z; v.w += a.w;
  }
  float* obase = out + (size_t)b * NS * NP + p4;
#pragma unroll 4
  for (int ss = 0; ss < 32; ++ss) {
    int s = sc * 32 + ss;
    *(float4*)(obase + (size_t)s * NP) = v;
  }
}

extern "C" void kernel_launch(void* const* d_in, const int* in_sizes, int n_in,
                              void* d_out, int out_size, void* d_ws, size_t ws_size,
                              hipStream_t stream) {
  const float* f3d = (const float*)d_in[0];
  const float* f2d = (const float*)d_in[1];
  const float* ftx = (const float*)d_in[2];
  const float* W3d = (const float*)d_in[3];
  const float* b3d = (const float*)d_in[4];
  const float* W2d = (const float*)d_in[5];
  const float* b2d = (const float*)d_in[6];
  const float* Wf  = (const float*)d_in[7];
  const float* bfv = (const float*)d_in[8];
  float* out = (float*)d_out;
  float* ws = (float*)d_ws;

  // ws layout (floats)
  float* c0     = ws;                  // 294912
  float* c1     = ws + 294912;
  float* c2     = ws + 589824;
  float* c3     = ws + 884736;
  float* g_part = ws + 1179648;        // 786432
  float* sraw   = ws + 1966080;        // 8192
  float* p2f    = ws + 1974272;        // 4*32*768 = 98304
  float* ml     = ws + 2072576;        // 4096
  float* Pt     = ws + 2076672;        // 64*32*3072 = 6291456
  float* fpart  = ws + 8368128;        // 16*32*3072 = 1572864 (end ~39.8 MB)

  k1_f3p<<<384, 256, 0, stream>>>(f3d, W3d, b3d, c0, c1, c2, c3);
  kT_text<<<512, 256, 0, stream>>>(ftx, c0, Pt, ml);
  k2_gpart<<<96, 256, 0, stream>>>(W2d, c0, g_part);
  k3a_scores<<<256, 256, 0, stream>>>(f2d, g_part, sraw);
  kComb<<<96, 256, 0, stream>>>(Pt, ml, c0, c1, c2, c3);
  k3c_sm<<<384, 256, 0, stream>>>(f2d, sraw, p2f);
  k5_pool2d<<<192, 256, 0, stream>>>(W2d, b2d, p2f, c0, c1, c2, c3);
  k_csum<<<288, 256, 0, stream>>>(c0, c1, c2, c3);
  k6_fused<<<512, 256, 0, stream>>>(Wf, c0, fpart);
  k7_bcast<<<768, 256, 0, stream>>>(fpart, bfv, out);
}